// Round 7
// baseline (437.629 us; speedup 1.0000x reference)
//
#include <hip/hip_runtime.h>
#include <math.h>

#define N_NODES 50000
#define N_EDGES 800000

typedef short bf8 __attribute__((ext_vector_type(8)));    // 8 bf16 (A/B frag)
typedef float f4x __attribute__((ext_vector_type(4)));    // C/D frag
typedef float f2v __attribute__((ext_vector_type(2)));    // packed fp32
typedef unsigned short us8 __attribute__((ext_vector_type(8)));  // 16B bf16

__device__ __forceinline__ unsigned short f2bf(float x) {
  unsigned u = __float_as_uint(x);
  unsigned r = (u + 0x7fff + ((u >> 16) & 1)) >> 16;  // RNE
  return (unsigned short)r;
}
__device__ __forceinline__ float bf2f(unsigned short b) {
  return __uint_as_float(((unsigned)b) << 16);
}
__device__ __forceinline__ unsigned pack2(float lo, float hi) {
  return (unsigned)f2bf(lo) | ((unsigned)f2bf(hi) << 16);
}
__device__ __forceinline__ f2v bfpair(unsigned d) {
  f2v r;
  r.x = __uint_as_float(d << 16);
  r.y = __uint_as_float(d & 0xffff0000u);
  return r;
}

// ---------------------------------------------------------------------------
// MFMA GEMM + fused el/er epilogue. Double-buffered LDS: one barrier/K-iter;
// next tile's global loads overlap MFMA on current tile.
// BM=128, BN=64 (= one head), BK=32; 256 thr = 4 waves; 2x4 16x16 tiles/wave.
// ---------------------------------------------------------------------------
template <int ABF16>
__global__ __launch_bounds__(256) void gemm_mfma_k(
    const void* __restrict__ Xv, const float* __restrict__ W,
    unsigned short* __restrict__ Yb, float* __restrict__ el,
    float* __restrict__ er, const float* __restrict__ al,
    const float* __restrict__ ar, int N, int K, int M) {
  __shared__ unsigned short As[2][128][40];  // [buf][m][k], +8 pad
  __shared__ unsigned short Bs[2][64][40];   // [buf][n][k], +8 pad
  const int tile_n = blockIdx.x * 128;
  const int cb = blockIdx.y * 64;  // == head*64
  const int t = threadIdx.x;
  const int wave = t >> 6, lane = t & 63;
  const int quad = lane >> 4, l16 = lane & 15;

  f4x acc[2][4];
#pragma unroll
  for (int i = 0; i < 2; ++i)
#pragma unroll
    for (int j = 0; j < 4; ++j) acc[i][j] = (f4x){0.f, 0.f, 0.f, 0.f};

  const int ar_ = t >> 1;        // A stage row (0..127)
  const int ac0 = (t & 1) * 16;  // A stage k base
  const int bn = t & 63;         // B stage col
  const int bkq = t >> 6;        // B stage k-quad
  const int gr = tile_n + ar_;

  uint4 a_u0, a_u1, b_u;
  auto load_tile = [&](int k0) {
    if (ABF16) {
      const unsigned short* Xb = (const unsigned short*)Xv;
      us8 u0 = (us8)0, u1 = (us8)0;
      if (gr < N) {
        const unsigned short* s = Xb + (size_t)gr * K + k0 + ac0;
        u0 = *(const us8*)(s + 0);
        u1 = *(const us8*)(s + 8);
      }
      a_u0 = *(const uint4*)&u0;
      a_u1 = *(const uint4*)&u1;
    } else {
      const float* X = (const float*)Xv;
      if (gr < N) {
        const float* s = X + (size_t)gr * K + k0 + ac0;
        float4 a = *(const float4*)(s + 0);
        float4 b = *(const float4*)(s + 4);
        float4 c = *(const float4*)(s + 8);
        float4 d = *(const float4*)(s + 12);
        a_u0 = make_uint4(pack2(a.x, a.y), pack2(a.z, a.w),
                          pack2(b.x, b.y), pack2(b.z, b.w));
        a_u1 = make_uint4(pack2(c.x, c.y), pack2(c.z, c.w),
                          pack2(d.x, d.y), pack2(d.z, d.w));
      } else {
        a_u0 = make_uint4(0, 0, 0, 0);
        a_u1 = make_uint4(0, 0, 0, 0);
      }
    }
    const float* s = W + (size_t)(k0 + bkq * 8) * M + cb + bn;
    float w0 = s[0 * M], w1 = s[1 * M], w2 = s[2 * M], w3 = s[3 * M];
    float w4 = s[4 * M], w5 = s[5 * M], w6 = s[6 * M], w7 = s[7 * M];
    b_u = make_uint4(pack2(w0, w1), pack2(w2, w3), pack2(w4, w5),
                     pack2(w6, w7));
  };

  load_tile(0);
  int cur = 0;
  for (int k0 = 0; k0 < K; k0 += 32) {
    *(uint4*)&As[cur][ar_][ac0] = a_u0;
    *(uint4*)&As[cur][ar_][ac0 + 8] = a_u1;
    *(uint4*)&Bs[cur][bn][bkq * 8] = b_u;
    __syncthreads();
    if (k0 + 32 < K) load_tile(k0 + 32);  // in flight during MFMA
    bf8 afrag[2], bfrag[4];
#pragma unroll
    for (int rt = 0; rt < 2; ++rt)
      afrag[rt] = *(const bf8*)&As[cur][wave * 32 + rt * 16 + l16][quad * 8];
#pragma unroll
    for (int ct = 0; ct < 4; ++ct)
      bfrag[ct] = *(const bf8*)&Bs[cur][ct * 16 + l16][quad * 8];
#pragma unroll
    for (int rt = 0; rt < 2; ++rt)
#pragma unroll
      for (int ct = 0; ct < 4; ++ct)
        acc[rt][ct] = __builtin_amdgcn_mfma_f32_16x16x32_bf16(
            afrag[rt], bfrag[ct], acc[rt][ct], 0, 0, 0);
    cur ^= 1;  // next store goes to other buffer; 1-iter skew is safe
  }
  const int H = M >> 6;
  const int head = cb >> 6;
  float al4[4], ar4[4];
#pragma unroll
  for (int ct = 0; ct < 4; ++ct) {
    al4[ct] = al[cb + ct * 16 + l16];
    ar4[ct] = ar[cb + ct * 16 + l16];
  }
#pragma unroll
  for (int rt = 0; rt < 2; ++rt) {
#pragma unroll
    for (int r = 0; r < 4; ++r) {
      int row = tile_n + wave * 32 + rt * 16 + quad * 4 + r;
      float pl = 0.f, pr = 0.f;
#pragma unroll
      for (int ct = 0; ct < 4; ++ct) {
        float y = acc[rt][ct][r];
        pl += y * al4[ct];
        pr += y * ar4[ct];
        if (row < N) Yb[(size_t)row * M + cb + ct * 16 + l16] = f2bf(y);
      }
#pragma unroll
      for (int off = 1; off < 16; off <<= 1) {
        pl += __shfl_xor(pl, off);
        pr += __shfl_xor(pr, off);
      }
      if (l16 == 0 && row < N) {
        el[row * H + head] = pl;
        er[row * H + head] = pr;
      }
    }
  }
}

// ---------------------------------------------------------------------------
// CSR build (2 edges per thread)
// ---------------------------------------------------------------------------
__global__ __launch_bounds__(256) void count_deg_k(
    const int2* __restrict__ dst2, int* __restrict__ deg, int E2) {
  int i = blockIdx.x * blockDim.x + threadIdx.x;
  if (i < E2) {
    int2 d = dst2[i];
    atomicAdd(&deg[d.x], 1);
    atomicAdd(&deg[d.y], 1);
  }
}

__global__ __launch_bounds__(256) void alloc_rows_k(
    const int* __restrict__ deg, int* __restrict__ rowstart,
    int* __restrict__ cursor, int* __restrict__ gcounter, int N) {
  int i = blockIdx.x * blockDim.x + threadIdx.x;
  int lane = threadIdx.x & 63;
  int d = (i < N) ? deg[i] : 0;
  int x = d;
#pragma unroll
  for (int off = 1; off < 64; off <<= 1) {
    int t = __shfl_up(x, off);
    if (lane >= off) x += t;
  }
  int wsum = __shfl(x, 63);
  int base = 0;
  if (lane == 63) base = atomicAdd(gcounter, wsum);
  base = __shfl(base, 63);
  if (i < N) {
    int mystart = base + x - d;
    rowstart[i] = mystart;
    cursor[i] = mystart;
  }
}

__global__ __launch_bounds__(256) void scatter_k(
    const int2* __restrict__ src2, const int2* __restrict__ dst2,
    int* __restrict__ cursor, int* __restrict__ src_sorted, int E2) {
  int i = blockIdx.x * blockDim.x + threadIdx.x;
  if (i < E2) {
    int2 s = src2[i];
    int2 d = dst2[i];
    int p0 = atomicAdd(&cursor[d.x], 1);
    src_sorted[p0] = s.x;
    int p1 = atomicAdd(&cursor[d.y], 1);
    src_sorted[p1] = s.y;
  }
}

// ---------------------------------------------------------------------------
// Fused softmax + aggregation, H=4, F=64, bf16 h. One wave per dst node.
// Pass 1 (lane = slot*4+head): ex=exp(leakyrelu(el+er)) -> albuf + head sums.
// Pass 2: half-wave per edge (32 lanes x 16B = 512B row), 4 edges per
// half-wave in flight (R5 shape: best occupancy); packed f32 math;
// wave-local s_waitcnt instead of barrier.
// ---------------------------------------------------------------------------
template <int RELU>
__global__ __launch_bounds__(256) void node_agg4_k(
    const unsigned short* __restrict__ hb, const float* __restrict__ el,
    const float* __restrict__ er, const int* __restrict__ rowstart,
    const int* __restrict__ rowend, const int* __restrict__ src_sorted,
    float* __restrict__ albuf, const float* __restrict__ bias,
    unsigned short* __restrict__ outb, int N) {
  int node = blockIdx.x * 4 + (threadIdx.x >> 6);
  int lane = threadIdx.x & 63;
  if (node >= N) return;
  int start = rowstart[node], end = rowend[node];
  int head1 = lane & 3;
  int slot = lane >> 2;
  float er_v = er[node * 4 + head1];
  float ssum = 0.f;
  for (int p = start + slot; p < end; p += 16) {
    int s = src_sorted[p];
    float v = el[s * 4 + head1] + er_v;
    v = (v >= 0.f) ? v : 0.2f * v;
    float ex = __expf(v);
    ssum += ex;
    albuf[p * 4 + head1] = ex;  // coalesced
  }
#pragma unroll
  for (int off = 4; off < 64; off <<= 1) ssum += __shfl_xor(ssum, off);
  float inv_s = (end > start) ? 1.f / ssum : 0.f;
  int eslot = lane >> 5;  // which edge of the pair
  int flane = lane & 31;  // 16B feature chunk
  int fo8 = flane << 3;
  int headf = fo8 >> 6;
  float inv_f = __shfl(inv_s, headf);
  __builtin_amdgcn_s_waitcnt(0);  // drain own albuf stores (wave-local dep)
  f2v acc2[4];
#pragma unroll
  for (int q = 0; q < 4; ++q) acc2[q] = (f2v){0.f, 0.f};
  if (end > start) {
    int src_first = src_sorted[start];
    for (int p0 = start; p0 < end; p0 += 8) {
      int sj[4];
      float aj[4];
#pragma unroll
      for (int j = 0; j < 4; ++j) {
        int p = p0 + 2 * j + eslot;
        bool v = p < end;
        sj[j] = v ? src_sorted[p] : src_first;  // clamped: L1-hot row
        aj[j] = v ? albuf[p * 4 + headf] : 0.f;
      }
#pragma unroll
      for (int j = 0; j < 4; ++j) {
        uint4 d = *(const uint4*)(hb + (size_t)sj[j] * 256 + fo8);
        f2v a2 = (f2v){aj[j], aj[j]};
        acc2[0] += bfpair(d.x) * a2;
        acc2[1] += bfpair(d.y) * a2;
        acc2[2] += bfpair(d.z) * a2;
        acc2[3] += bfpair(d.w) * a2;
      }
    }
  }
  float acc[8];
#pragma unroll
  for (int q = 0; q < 4; ++q) {
    acc[2 * q] = acc2[q].x;
    acc[2 * q + 1] = acc2[q].y;
  }
#pragma unroll
  for (int q = 0; q < 8; ++q) acc[q] += __shfl_xor(acc[q], 32);
  if (eslot == 0) {
    us8 o;
#pragma unroll
    for (int q = 0; q < 8; ++q) {
      float v = acc[q] * inv_f + bias[fo8 + q];
      if (RELU) v = fmaxf(v, 0.f);
      o[q] = f2bf(v);
    }
    *(us8*)(outb + (size_t)node * 256 + fo8) = o;
  }
}

// H=1, F=64: 8 lanes x 16B = 128B row; 8 edge-slots, 2-deep unroll -> 16
// edges in flight. fp32 output (final layer).
__global__ __launch_bounds__(256) void node_agg1_k(
    const unsigned short* __restrict__ hb, const float* __restrict__ el,
    const float* __restrict__ er, const int* __restrict__ rowstart,
    const int* __restrict__ rowend, const int* __restrict__ src_sorted,
    float* __restrict__ albuf, const float* __restrict__ bias,
    float* __restrict__ out, int N) {
  int node = blockIdx.x * 4 + (threadIdx.x >> 6);
  int lane = threadIdx.x & 63;
  if (node >= N) return;
  int start = rowstart[node], end = rowend[node];
  float er_v = er[node];
  float ssum = 0.f;
  for (int p = start + lane; p < end; p += 64) {
    float v = el[src_sorted[p]] + er_v;
    v = (v >= 0.f) ? v : 0.2f * v;
    float ex = __expf(v);
    ssum += ex;
    albuf[p] = ex;
  }
#pragma unroll
  for (int off = 1; off < 64; off <<= 1) ssum += __shfl_xor(ssum, off);
  float inv_s = (end > start) ? 1.f / ssum : 0.f;
  int eslot = lane >> 3;  // 0..7
  int flane = lane & 7;
  int fo8 = flane << 3;
  __builtin_amdgcn_s_waitcnt(0);
  f2v acc2[4];
#pragma unroll
  for (int q = 0; q < 4; ++q) acc2[q] = (f2v){0.f, 0.f};
  if (end > start) {
    int src_first = src_sorted[start];
    for (int p0 = start; p0 < end; p0 += 16) {
      int sj[2];
      float aj[2];
#pragma unroll
      for (int j = 0; j < 2; ++j) {
        int p = p0 + 8 * j + eslot;
        bool v = p < end;
        sj[j] = v ? src_sorted[p] : src_first;
        aj[j] = v ? albuf[p] : 0.f;
      }
#pragma unroll
      for (int j = 0; j < 2; ++j) {
        uint4 d = *(const uint4*)(hb + (size_t)sj[j] * 64 + fo8);
        f2v a2 = (f2v){aj[j], aj[j]};
        acc2[0] += bfpair(d.x) * a2;
        acc2[1] += bfpair(d.y) * a2;
        acc2[2] += bfpair(d.z) * a2;
        acc2[3] += bfpair(d.w) * a2;
      }
    }
  }
  float acc[8];
#pragma unroll
  for (int q = 0; q < 4; ++q) {
    acc[2 * q] = acc2[q].x;
    acc[2 * q + 1] = acc2[q].y;
  }
#pragma unroll
  for (int off = 8; off < 64; off <<= 1)
#pragma unroll
    for (int q = 0; q < 8; ++q) acc[q] += __shfl_xor(acc[q], off);
  if (eslot == 0) {
    float* o = out + (size_t)node * 64 + fo8;
#pragma unroll
    for (int q = 0; q < 8; ++q) o[q] = acc[q] * inv_s + bias[fo8 + q];
  }
}

// ---------------------------------------------------------------------------
extern "C" void kernel_launch(void* const* d_in, const int* in_sizes, int n_in,
                              void* d_out, int out_size, void* d_ws,
                              size_t ws_size, hipStream_t stream) {
  const float* feat = (const float*)d_in[0];
  const int* src = (const int*)d_in[1];
  const int* dst = (const int*)d_in[2];
  const float* W1 = (const float*)d_in[3];
  const float* al1 = (const float*)d_in[4];
  const float* ar1 = (const float*)d_in[5];
  const float* b1 = (const float*)d_in[6];
  const float* W2 = (const float*)d_in[7];
  const float* al2 = (const float*)d_in[8];
  const float* ar2 = (const float*)d_in[9];
  const float* b2 = (const float*)d_in[10];
  const float* W3 = (const float*)d_in[11];
  const float* al3 = (const float*)d_in[12];
  const float* ar3 = (const float*)d_in[13];
  const float* b3 = (const float*)d_in[14];
  float* out = (float*)d_out;

  unsigned short* hb = (unsigned short*)d_ws;             // N*256 bf16
  unsigned short* fb = hb + (size_t)N_NODES * 256;        // N*256 bf16
  float* el = (float*)(fb + (size_t)N_NODES * 256);       // N*4
  float* er = el + (size_t)N_NODES * 4;                   // N*4
  int* rowstart = (int*)(er + (size_t)N_NODES * 4);       // N
  int* cursor = rowstart + N_NODES;                       // N
  int* deg = cursor + N_NODES;                            // N
  int* gcounter = deg + N_NODES;                          // 1
  int* src_sorted = gcounter + 1;                         // E
  float* albuf = (float*)(src_sorted + N_EDGES);          // E*4

  const int N = N_NODES, E = N_EDGES;
  const int E2 = E / 2;
  const int GX = (N + 127) / 128;

  // ---- CSR build ----
  hipMemsetAsync(deg, 0, (size_t)(N + 1) * sizeof(int), stream);
  hipLaunchKernelGGL(count_deg_k, dim3((E2 + 255) / 256), dim3(256), 0, stream,
                     (const int2*)dst, deg, E2);
  hipLaunchKernelGGL(alloc_rows_k, dim3((N + 255) / 256), dim3(256), 0, stream,
                     deg, rowstart, cursor, gcounter, N);
  hipLaunchKernelGGL(scatter_k, dim3((E2 + 255) / 256), dim3(256), 0, stream,
                     (const int2*)src, (const int2*)dst, cursor, src_sorted,
                     E2);
  // after scatter, cursor[i] == row end

  // ---- Layer 1: feat[N,128] -> fb[N,256] (bf16), relu ----
  hipLaunchKernelGGL((gemm_mfma_k<0>), dim3(GX, 4), dim3(256), 0, stream, feat,
                     W1, hb, el, er, al1, ar1, N, 128, 256);
  hipLaunchKernelGGL((node_agg4_k<1>), dim3((N + 3) / 4), dim3(256), 0, stream,
                     hb, el, er, rowstart, cursor, src_sorted, albuf, b1, fb,
                     N);

  // ---- Layer 2: fb[N,256] -> fb[N,256] (bf16), relu ----
  hipLaunchKernelGGL((gemm_mfma_k<1>), dim3(GX, 4), dim3(256), 0, stream, fb,
                     W2, hb, el, er, al2, ar2, N, 256, 256);
  hipLaunchKernelGGL((node_agg4_k<1>), dim3((N + 3) / 4), dim3(256), 0, stream,
                     hb, el, er, rowstart, cursor, src_sorted, albuf, b2, fb,
                     N);

  // ---- Layer 3: fb[N,256] -> out[N,64] (fp32) ----
  hipLaunchKernelGGL((gemm_mfma_k<1>), dim3(GX, 1), dim3(256), 0, stream, fb,
                     W3, hb, el, er, al3, ar3, N, 256, 64);
  hipLaunchKernelGGL(node_agg1_k, dim3((N + 3) / 4), dim3(256), 0, stream, hb,
                     el, er, rowstart, cursor, src_sorted, albuf, b3, out, N);
}

// Round 8
// 420.401 us; speedup vs baseline: 1.0410x; 1.0410x over previous
//
#include <hip/hip_runtime.h>
#include <math.h>

#define N_NODES 50000
#define N_EDGES 800000

typedef short bf8 __attribute__((ext_vector_type(8)));    // 8 bf16 (A/B frag)
typedef float f4x __attribute__((ext_vector_type(4)));    // C/D frag
typedef float f2v __attribute__((ext_vector_type(2)));    // packed fp32
typedef unsigned short us8 __attribute__((ext_vector_type(8)));  // 16B bf16

__device__ __forceinline__ unsigned short f2bf(float x) {
  unsigned u = __float_as_uint(x);
  unsigned r = (u + 0x7fff + ((u >> 16) & 1)) >> 16;  // RNE
  return (unsigned short)r;
}
__device__ __forceinline__ float bf2f(unsigned short b) {
  return __uint_as_float(((unsigned)b) << 16);
}
__device__ __forceinline__ unsigned pack2(float lo, float hi) {
  return (unsigned)f2bf(lo) | ((unsigned)f2bf(hi) << 16);
}
__device__ __forceinline__ f2v bfpair(unsigned d) {
  f2v r;
  r.x = __uint_as_float(d << 16);
  r.y = __uint_as_float(d & 0xffff0000u);
  return r;
}

// ---------------------------------------------------------------------------
// MFMA GEMM + fused el/er epilogue (single-buffer: best measured at small K).
// BM=128, BN=64 (= one head), BK=32; 256 thr = 4 waves; 2x4 16x16 tiles/wave.
// ---------------------------------------------------------------------------
template <int ABF16>
__global__ __launch_bounds__(256) void gemm_mfma_k(
    const void* __restrict__ Xv, const float* __restrict__ W,
    unsigned short* __restrict__ Yb, float* __restrict__ el,
    float* __restrict__ er, const float* __restrict__ al,
    const float* __restrict__ ar, int N, int K, int M) {
  __shared__ unsigned short As[128][40];  // [m][k], +8 pad
  __shared__ unsigned short Bs[64][40];   // [n][k], +8 pad
  const int tile_n = blockIdx.x * 128;
  const int cb = blockIdx.y * 64;  // == head*64
  const int t = threadIdx.x;
  const int wave = t >> 6, lane = t & 63;
  const int quad = lane >> 4, l16 = lane & 15;

  f4x acc[2][4];
#pragma unroll
  for (int i = 0; i < 2; ++i)
#pragma unroll
    for (int j = 0; j < 4; ++j) acc[i][j] = (f4x){0.f, 0.f, 0.f, 0.f};

  const int ar_ = t >> 1;
  const int ac0 = (t & 1) * 16;
  const int bn = t & 63;
  const int bkq = t >> 6;

  for (int k0 = 0; k0 < K; k0 += 32) {
    if (ABF16) {
      const unsigned short* Xb = (const unsigned short*)Xv;
      int gr = tile_n + ar_;
      us8 u0 = (us8)0, u1 = (us8)0;
      if (gr < N) {
        const unsigned short* s = Xb + (size_t)gr * K + k0 + ac0;
        u0 = *(const us8*)(s + 0);
        u1 = *(const us8*)(s + 8);
      }
      *(us8*)&As[ar_][ac0] = u0;
      *(us8*)&As[ar_][ac0 + 8] = u1;
    } else {
      const float* X = (const float*)Xv;
      int gr = tile_n + ar_;
      uint4 u0, u1;
      if (gr < N) {
        const float* s = X + (size_t)gr * K + k0 + ac0;
        float4 a = *(const float4*)(s + 0);
        float4 b = *(const float4*)(s + 4);
        float4 c = *(const float4*)(s + 8);
        float4 d = *(const float4*)(s + 12);
        u0 = make_uint4(pack2(a.x, a.y), pack2(a.z, a.w),
                        pack2(b.x, b.y), pack2(b.z, b.w));
        u1 = make_uint4(pack2(c.x, c.y), pack2(c.z, c.w),
                        pack2(d.x, d.y), pack2(d.z, d.w));
      } else {
        u0 = make_uint4(0, 0, 0, 0);
        u1 = make_uint4(0, 0, 0, 0);
      }
      *(uint4*)&As[ar_][ac0] = u0;
      *(uint4*)&As[ar_][ac0 + 8] = u1;
    }
    {
      const float* s = W + (size_t)(k0 + bkq * 8) * M + cb + bn;
      float w0 = s[0 * M], w1 = s[1 * M], w2 = s[2 * M], w3 = s[3 * M];
      float w4 = s[4 * M], w5 = s[5 * M], w6 = s[6 * M], w7 = s[7 * M];
      uint4 u = make_uint4(pack2(w0, w1), pack2(w2, w3), pack2(w4, w5),
                           pack2(w6, w7));
      *(uint4*)&Bs[bn][bkq * 8] = u;
    }
    __syncthreads();
    bf8 afrag[2], bfrag[4];
#pragma unroll
    for (int rt = 0; rt < 2; ++rt)
      afrag[rt] = *(const bf8*)&As[wave * 32 + rt * 16 + l16][quad * 8];
#pragma unroll
    for (int ct = 0; ct < 4; ++ct)
      bfrag[ct] = *(const bf8*)&Bs[ct * 16 + l16][quad * 8];
#pragma unroll
    for (int rt = 0; rt < 2; ++rt)
#pragma unroll
      for (int ct = 0; ct < 4; ++ct)
        acc[rt][ct] = __builtin_amdgcn_mfma_f32_16x16x32_bf16(
            afrag[rt], bfrag[ct], acc[rt][ct], 0, 0, 0);
    __syncthreads();
  }
  const int H = M >> 6;
  const int head = cb >> 6;
  float al4[4], ar4[4];
#pragma unroll
  for (int ct = 0; ct < 4; ++ct) {
    al4[ct] = al[cb + ct * 16 + l16];
    ar4[ct] = ar[cb + ct * 16 + l16];
  }
#pragma unroll
  for (int rt = 0; rt < 2; ++rt) {
#pragma unroll
    for (int r = 0; r < 4; ++r) {
      int row = tile_n + wave * 32 + rt * 16 + quad * 4 + r;
      float pl = 0.f, pr = 0.f;
#pragma unroll
      for (int ct = 0; ct < 4; ++ct) {
        float y = acc[rt][ct][r];
        pl += y * al4[ct];
        pr += y * ar4[ct];
        if (row < N) Yb[(size_t)row * M + cb + ct * 16 + l16] = f2bf(y);
      }
#pragma unroll
      for (int off = 1; off < 16; off <<= 1) {
        pl += __shfl_xor(pl, off);
        pr += __shfl_xor(pr, off);
      }
      if (l16 == 0 && row < N) {
        el[row * H + head] = pl;
        er[row * H + head] = pr;
      }
    }
  }
}

// ---------------------------------------------------------------------------
// CSR build (4 edges per thread, int4 loads)
// ---------------------------------------------------------------------------
__global__ __launch_bounds__(256) void count_deg_k(
    const int4* __restrict__ dst4, int* __restrict__ deg, int E4) {
  int i = blockIdx.x * blockDim.x + threadIdx.x;
  if (i < E4) {
    int4 d = dst4[i];
    atomicAdd(&deg[d.x], 1);
    atomicAdd(&deg[d.y], 1);
    atomicAdd(&deg[d.z], 1);
    atomicAdd(&deg[d.w], 1);
  }
}

__global__ __launch_bounds__(256) void alloc_rows_k(
    const int* __restrict__ deg, int* __restrict__ rowstart,
    int* __restrict__ cursor, int* __restrict__ gcounter, int N) {
  int i = blockIdx.x * blockDim.x + threadIdx.x;
  int lane = threadIdx.x & 63;
  int d = (i < N) ? deg[i] : 0;
  int x = d;
#pragma unroll
  for (int off = 1; off < 64; off <<= 1) {
    int t = __shfl_up(x, off);
    if (lane >= off) x += t;
  }
  int wsum = __shfl(x, 63);
  int base = 0;
  if (lane == 63) base = atomicAdd(gcounter, wsum);
  base = __shfl(base, 63);
  if (i < N) {
    int mystart = base + x - d;
    rowstart[i] = mystart;
    cursor[i] = mystart;
  }
}

__global__ __launch_bounds__(256) void scatter_k(
    const int4* __restrict__ src4, const int4* __restrict__ dst4,
    int* __restrict__ cursor, int* __restrict__ src_sorted, int E4) {
  int i = blockIdx.x * blockDim.x + threadIdx.x;
  if (i < E4) {
    int4 s = src4[i];
    int4 d = dst4[i];
    int p0 = atomicAdd(&cursor[d.x], 1);
    src_sorted[p0] = s.x;
    int p1 = atomicAdd(&cursor[d.y], 1);
    src_sorted[p1] = s.y;
    int p2 = atomicAdd(&cursor[d.z], 1);
    src_sorted[p2] = s.z;
    int p3 = atomicAdd(&cursor[d.w], 1);
    src_sorted[p3] = s.w;
  }
}

// ---------------------------------------------------------------------------
// Fused softmax + aggregation, H=4, F=64, bf16 h. One wave per dst node.
// ---------------------------------------------------------------------------
template <int RELU>
__global__ __launch_bounds__(256) void node_agg4_k(
    const unsigned short* __restrict__ hb, const float* __restrict__ el,
    const float* __restrict__ er, const int* __restrict__ rowstart,
    const int* __restrict__ rowend, const int* __restrict__ src_sorted,
    float* __restrict__ albuf, const float* __restrict__ bias,
    unsigned short* __restrict__ outb, int N) {
  int node = blockIdx.x * 4 + (threadIdx.x >> 6);
  int lane = threadIdx.x & 63;
  if (node >= N) return;
  int start = rowstart[node], end = rowend[node];
  int head1 = lane & 3;
  int slot = lane >> 2;
  float er_v = er[node * 4 + head1];
  float ssum = 0.f;
  for (int p = start + slot; p < end; p += 16) {
    int s = src_sorted[p];
    float v = el[s * 4 + head1] + er_v;
    v = (v >= 0.f) ? v : 0.2f * v;
    float ex = __expf(v);
    ssum += ex;
    albuf[p * 4 + head1] = ex;  // coalesced
  }
#pragma unroll
  for (int off = 4; off < 64; off <<= 1) ssum += __shfl_xor(ssum, off);
  float inv_s = (end > start) ? 1.f / ssum : 0.f;
  int eslot = lane >> 5;
  int flane = lane & 31;
  int fo8 = flane << 3;
  int headf = fo8 >> 6;
  float inv_f = __shfl(inv_s, headf);
  __builtin_amdgcn_s_waitcnt(0);  // drain own albuf stores (wave-local dep)
  f2v acc2[4];
#pragma unroll
  for (int q = 0; q < 4; ++q) acc2[q] = (f2v){0.f, 0.f};
  if (end > start) {
    int src_first = src_sorted[start];
    for (int p0 = start; p0 < end; p0 += 8) {
      int sj[4];
      float aj[4];
#pragma unroll
      for (int j = 0; j < 4; ++j) {
        int p = p0 + 2 * j + eslot;
        bool v = p < end;
        sj[j] = v ? src_sorted[p] : src_first;  // clamped: L1-hot row
        aj[j] = v ? albuf[p * 4 + headf] : 0.f;
      }
#pragma unroll
      for (int j = 0; j < 4; ++j) {
        uint4 d = *(const uint4*)(hb + (size_t)sj[j] * 256 + fo8);
        f2v a2 = (f2v){aj[j], aj[j]};
        acc2[0] += bfpair(d.x) * a2;
        acc2[1] += bfpair(d.y) * a2;
        acc2[2] += bfpair(d.z) * a2;
        acc2[3] += bfpair(d.w) * a2;
      }
    }
  }
  float acc[8];
#pragma unroll
  for (int q = 0; q < 4; ++q) {
    acc[2 * q] = acc2[q].x;
    acc[2 * q + 1] = acc2[q].y;
  }
#pragma unroll
  for (int q = 0; q < 8; ++q) acc[q] += __shfl_xor(acc[q], 32);
  if (eslot == 0) {
    us8 o;
#pragma unroll
    for (int q = 0; q < 8; ++q) {
      float v = acc[q] * inv_f + bias[fo8 + q];
      if (RELU) v = fmaxf(v, 0.f);
      o[q] = f2bf(v);
    }
    *(us8*)(outb + (size_t)node * 256 + fo8) = o;
  }
}

// H=1, F=64: 8 lanes x 16B = 128B row; 8 edge-slots, 2-deep unroll.
__global__ __launch_bounds__(256) void node_agg1_k(
    const unsigned short* __restrict__ hb, const float* __restrict__ el,
    const float* __restrict__ er, const int* __restrict__ rowstart,
    const int* __restrict__ rowend, const int* __restrict__ src_sorted,
    float* __restrict__ albuf, const float* __restrict__ bias,
    float* __restrict__ out, int N) {
  int node = blockIdx.x * 4 + (threadIdx.x >> 6);
  int lane = threadIdx.x & 63;
  if (node >= N) return;
  int start = rowstart[node], end = rowend[node];
  float er_v = er[node];
  float ssum = 0.f;
  for (int p = start + lane; p < end; p += 64) {
    float v = el[src_sorted[p]] + er_v;
    v = (v >= 0.f) ? v : 0.2f * v;
    float ex = __expf(v);
    ssum += ex;
    albuf[p] = ex;
  }
#pragma unroll
  for (int off = 1; off < 64; off <<= 1) ssum += __shfl_xor(ssum, off);
  float inv_s = (end > start) ? 1.f / ssum : 0.f;
  int eslot = lane >> 3;
  int flane = lane & 7;
  int fo8 = flane << 3;
  __builtin_amdgcn_s_waitcnt(0);
  f2v acc2[4];
#pragma unroll
  for (int q = 0; q < 4; ++q) acc2[q] = (f2v){0.f, 0.f};
  if (end > start) {
    int src_first = src_sorted[start];
    for (int p0 = start; p0 < end; p0 += 16) {
      int sj[2];
      float aj[2];
#pragma unroll
      for (int j = 0; j < 2; ++j) {
        int p = p0 + 8 * j + eslot;
        bool v = p < end;
        sj[j] = v ? src_sorted[p] : src_first;
        aj[j] = v ? albuf[p] : 0.f;
      }
#pragma unroll
      for (int j = 0; j < 2; ++j) {
        uint4 d = *(const uint4*)(hb + (size_t)sj[j] * 64 + fo8);
        f2v a2 = (f2v){aj[j], aj[j]};
        acc2[0] += bfpair(d.x) * a2;
        acc2[1] += bfpair(d.y) * a2;
        acc2[2] += bfpair(d.z) * a2;
        acc2[3] += bfpair(d.w) * a2;
      }
    }
  }
  float acc[8];
#pragma unroll
  for (int q = 0; q < 4; ++q) {
    acc[2 * q] = acc2[q].x;
    acc[2 * q + 1] = acc2[q].y;
  }
#pragma unroll
  for (int off = 8; off < 64; off <<= 1)
#pragma unroll
    for (int q = 0; q < 8; ++q) acc[q] += __shfl_xor(acc[q], off);
  if (eslot == 0) {
    float* o = out + (size_t)node * 64 + fo8;
#pragma unroll
    for (int q = 0; q < 8; ++q) o[q] = acc[q] * inv_s + bias[fo8 + q];
  }
}

// ---------------------------------------------------------------------------
extern "C" void kernel_launch(void* const* d_in, const int* in_sizes, int n_in,
                              void* d_out, int out_size, void* d_ws,
                              size_t ws_size, hipStream_t stream) {
  const float* feat = (const float*)d_in[0];
  const int* src = (const int*)d_in[1];
  const int* dst = (const int*)d_in[2];
  const float* W1 = (const float*)d_in[3];
  const float* al1 = (const float*)d_in[4];
  const float* ar1 = (const float*)d_in[5];
  const float* b1 = (const float*)d_in[6];
  const float* W2 = (const float*)d_in[7];
  const float* al2 = (const float*)d_in[8];
  const float* ar2 = (const float*)d_in[9];
  const float* b2 = (const float*)d_in[10];
  const float* W3 = (const float*)d_in[11];
  const float* al3 = (const float*)d_in[12];
  const float* ar3 = (const float*)d_in[13];
  const float* b3 = (const float*)d_in[14];
  float* out = (float*)d_out;

  unsigned short* hb = (unsigned short*)d_ws;             // N*256 bf16
  unsigned short* fb = hb + (size_t)N_NODES * 256;        // N*256 bf16
  float* el = (float*)(fb + (size_t)N_NODES * 256);       // N*4
  float* er = el + (size_t)N_NODES * 4;                   // N*4
  int* rowstart = (int*)(er + (size_t)N_NODES * 4);       // N
  int* cursor = rowstart + N_NODES;                       // N
  int* deg = cursor + N_NODES;                            // N
  int* gcounter = deg + N_NODES;                          // 1
  int* src_sorted = gcounter + 1;                         // E
  float* albuf = (float*)(src_sorted + N_EDGES);          // E*4

  const int N = N_NODES, E = N_EDGES;
  const int E4 = E / 4;
  const int GX = (N + 127) / 128;

  // ---- CSR build ----
  hipMemsetAsync(deg, 0, (size_t)(N + 1) * sizeof(int), stream);
  hipLaunchKernelGGL(count_deg_k, dim3((E4 + 255) / 256), dim3(256), 0, stream,
                     (const int4*)dst, deg, E4);
  hipLaunchKernelGGL(alloc_rows_k, dim3((N + 255) / 256), dim3(256), 0, stream,
                     deg, rowstart, cursor, gcounter, N);
  hipLaunchKernelGGL(scatter_k, dim3((E4 + 255) / 256), dim3(256), 0, stream,
                     (const int4*)src, (const int4*)dst, cursor, src_sorted,
                     E4);
  // after scatter, cursor[i] == row end

  // ---- Layer 1: feat[N,128] -> fb[N,256] (bf16), relu ----
  hipLaunchKernelGGL((gemm_mfma_k<0>), dim3(GX, 4), dim3(256), 0, stream, feat,
                     W1, hb, el, er, al1, ar1, N, 128, 256);
  hipLaunchKernelGGL((node_agg4_k<1>), dim3((N + 3) / 4), dim3(256), 0, stream,
                     hb, el, er, rowstart, cursor, src_sorted, albuf, b1, fb,
                     N);

  // ---- Layer 2: fb[N,256] -> fb[N,256] (bf16), relu ----
  hipLaunchKernelGGL((gemm_mfma_k<1>), dim3(GX, 4), dim3(256), 0, stream, fb,
                     W2, hb, el, er, al2, ar2, N, 256, 256);
  hipLaunchKernelGGL((node_agg4_k<1>), dim3((N + 3) / 4), dim3(256), 0, stream,
                     hb, el, er, rowstart, cursor, src_sorted, albuf, b2, fb,
                     N);

  // ---- Layer 3: fb[N,256] -> out[N,64] (fp32) ----
  hipLaunchKernelGGL((gemm_mfma_k<1>), dim3(GX, 1), dim3(256), 0, stream, fb,
                     W3, hb, el, er, al3, ar3, N, 256, 64);
  hipLaunchKernelGGL(node_agg1_k, dim3((N + 3) / 4), dim3(256), 0, stream, hb,
                     el, er, rowstart, cursor, src_sorted, albuf, b3, out, N);
}